// Round 2
// baseline (8721.840 us; speedup 1.0000x reference)
//
#include <hip/hip_runtime.h>
#include <hip/hip_fp16.h>

#define T_STEPS 512
#define BDIM 512
#define LDIM 512
#define FDIM 128

typedef _Float16 half8 __attribute__((ext_vector_type(8)));
typedef float f4_t __attribute__((ext_vector_type(4)));

// workspace offsets (bytes), all 16B-aligned
#define OFF_WPERM   0u          // 2048*512*2   = 2097152
#define OFF_WDH     2097152u    // 128*512*2    = 131072
#define OFF_BCOMB   2228224u    // 2048*4       = 8192
#define OFF_HBUF0   2236416u    // 512*512*2    = 524288
#define OFF_HBUF1   2760704u    // 512*512*2
#define OFF_CTR     3284992u    // 8 groups * 128B = 1024
// total ~3.3 MB

__device__ __forceinline__ float sigmoidf_(float x) { return 1.f / (1.f + __expf(-x)); }
__device__ __forceinline__ float tanhf_(float x) { return 1.f - 2.f / (__expf(2.f * x) + 1.f); }

__device__ __forceinline__ void gload_lds16(const void* g, void* l) {
    __builtin_amdgcn_global_load_lds(
        (const __attribute__((address_space(1))) void*)g,
        (__attribute__((address_space(3))) void*)l, 16, 0, 0);
}

// ---------------- precompute: W_perm = permuted+swizzled fp16 of (W_hh + W_ih@W_dense), b_comb ----------------
// W_perm row pr = sg*4 + gate  (s-major ordering so MFMA C-layout makes i,f,g,o lane-local)
__global__ __launch_bounds__(256) void k_prep_w(
    const float* __restrict__ W_ih, const float* __restrict__ W_hh,
    const float* __restrict__ b_ih, const float* __restrict__ b_hh,
    const float* __restrict__ W_dense, const float* __restrict__ b_dense,
    _Float16* __restrict__ Wperm, float* __restrict__ bcomb)
{
    __shared__ float ih[FDIM];
    const int pr = blockIdx.x;            // 0..2047
    const int gate = pr & 3, sg = pr >> 2;
    const int j = gate * 512 + sg;        // original gate row
    const int tid = threadIdx.x;
    if (tid < FDIM) ih[tid] = W_ih[j * FDIM + tid];
    __syncthreads();
    const int k0 = tid * 2;
    float a0 = W_hh[(size_t)j * LDIM + k0];
    float a1 = W_hh[(size_t)j * LDIM + k0 + 1];
    for (int f = 0; f < FDIM; ++f) {
        const float w = ih[f];
        a0 += w * W_dense[f * LDIM + k0];
        a1 += w * W_dense[f * LDIM + k0 + 1];
    }
    const int s = (pr & 7) << 3;          // element-level XOR swizzle
    Wperm[(size_t)pr * LDIM + (k0 ^ s)] = (_Float16)a0;
    Wperm[(size_t)pr * LDIM + (k0 ^ s) + 1] = (_Float16)a1;
    if (tid == 0) {
        float acc = b_ih[j] + b_hh[j];
        for (int f = 0; f < FDIM; ++f) acc += ih[f] * b_dense[f];
        bcomb[j] = acc;
    }
}

// ---------------- precompute: fp16 swizzled W_dense copy + fp16 swizzled h0 ----------------
__global__ __launch_bounds__(256) void k_prep_misc(
    const float* __restrict__ W_dense, const float* __restrict__ h0,
    _Float16* __restrict__ Wdh, _Float16* __restrict__ hbuf0)
{
    const int bid = blockIdx.x, tid = threadIdx.x;
    const int k0 = tid * 2;
    if (bid < FDIM) {
        const int f = bid; const int s = (f & 7) << 3;
        Wdh[f * LDIM + (k0 ^ s)] = (_Float16)W_dense[f * LDIM + k0];
        Wdh[f * LDIM + (k0 ^ s) + 1] = (_Float16)W_dense[f * LDIM + k0 + 1];
    } else {
        const int r = bid - FDIM; const int s = (r & 7) << 3;
        hbuf0[r * LDIM + (k0 ^ s)] = (_Float16)h0[r * LDIM + k0];
        hbuf0[r * LDIM + (k0 ^ s) + 1] = (_Float16)h0[r * LDIM + k0 + 1];
    }
}

// ---------------- persistent recurrence kernel ----------------
// grid: (32 col-blocks, 8 row-groups) = 256 blocks = 1/CU (132KB LDS); block: 256 thr = 4 waves 2x2
// block tile: 64 gate-cols (16 L-cols x 4 gates, s-major) x 64 batch rows, K=512
#define LDS_W   0
#define LDS_WD  65536
#define LDS_H   69632
#define LDS_TOT 135168

__global__ __launch_bounds__(256, 1) void k_persist(
    const _Float16* __restrict__ Wperm, const _Float16* __restrict__ Wdh,
    const float* __restrict__ bcomb, const float* __restrict__ bdense,
    const float* __restrict__ c0,
    _Float16* __restrict__ hb0, _Float16* __restrict__ hb1,
    float* __restrict__ out, unsigned* __restrict__ ctr)
{
    __shared__ __align__(16) char smem[LDS_TOT];
    const int cb = blockIdx.x;      // 0..31 gate-col block
    const int g = blockIdx.y;       // 0..7 row group
    const int tid = threadIdx.x;
    const int w = tid >> 6, lane = tid & 63;
    const int wm = w >> 1, wn = w & 1;
    const int lr = lane & 15, lh = lane >> 4;

    // ---- one-time: stage W slice (64KB) + Wd slice (4KB) into LDS ----
    {
        const char* gw = (const char*)Wperm + (size_t)cb * 65536;
        #pragma unroll
        for (int i = 0; i < 16; ++i) {
            const int idx = i * 256 + tid;
            gload_lds16(gw + idx * 16, smem + LDS_W + idx * 16);
        }
        const char* gd = (const char*)Wdh + (size_t)cb * 4096;
        gload_lds16(gd + tid * 16, smem + LDS_WD + tid * 16);
    }

    // ---- hoist biases + c-state into registers ----
    float bi[2], bf[2], bg[2], bo[2];
    float creg[2][2];
    #pragma unroll
    for (int mt2 = 0; mt2 < 2; ++mt2) {
        const int sg = cb * 16 + 8 * wm + 4 * mt2 + lh;
        bi[mt2] = bcomb[0 * 512 + sg];
        bf[mt2] = bcomb[1 * 512 + sg];
        bg[mt2] = bcomb[2 * 512 + sg];
        bo[mt2] = bcomb[3 * 512 + sg];
        #pragma unroll
        for (int nt2 = 0; nt2 < 2; ++nt2) {
            const int row = g * 64 + (2 * wn + nt2) * 16 + lr;
            creg[mt2][nt2] = c0[(size_t)row * LDIM + sg];
        }
    }
    float bd[4];
    #pragma unroll
    for (int j = 0; j < 4; ++j) bd[j] = bdense[cb * 4 + j];

    const int ntx = 2 * wn + wm;                 // this wave's x output Ntile
    const int swA = (lr & 7) << 4;               // byte swizzle for W/h rows
    const int swD = ((cb * 4 + lr) & 7) << 4;    // Wd swizzle (global row)
    const char* pA0 = smem + LDS_W + ((2 * wm + 0) * 16 + lr) * 1024;
    const char* pA1 = smem + LDS_W + ((2 * wm + 1) * 16 + lr) * 1024;
    const char* pB0 = smem + LDS_H + ((2 * wn + 0) * 16 + lr) * 1024;
    const char* pB1 = smem + LDS_H + ((2 * wn + 1) * 16 + lr) * 1024;
    const char* pBx = smem + LDS_H + (ntx * 16 + lr) * 1024;
    const char* pD  = smem + LDS_WD + lr * 1024;

    unsigned* myctr = ctr + g * 32;              // 128B-spaced counters

    for (int t = 1; t <= T_STEPS; ++t) {
        const _Float16* hin = ((t - 1) & 1) ? hb1 : hb0;
        _Float16* hout = (t & 1) ? hb1 : hb0;

        if (t > 1) {
            if (tid == 0) {
                while (__hip_atomic_load(myctr, __ATOMIC_ACQUIRE, __HIP_MEMORY_SCOPE_AGENT) < 32u * (unsigned)(t - 1))
                    __builtin_amdgcn_s_sleep(1);
            }
            __syncthreads();
        }

        // ---- stage h slice 64KB (already swizzled in global) ----
        {
            const char* gh = (const char*)hin + (size_t)g * 65536;
            #pragma unroll
            for (int i = 0; i < 16; ++i) {
                const int idx = i * 256 + tid;
                gload_lds16(gh + idx * 16, smem + LDS_H + idx * 16);
            }
        }
        __syncthreads();

        f4_t acc[2][2] = {};
        f4_t accx = {};
        #pragma unroll
        for (int kt = 0; kt < 16; ++kt) {
            const int kb = kt * 64 + lh * 16;
            const half8 a0 = *(const half8*)(pA0 + (kb ^ swA));
            const half8 a1 = *(const half8*)(pA1 + (kb ^ swA));
            const half8 b0 = *(const half8*)(pB0 + (kb ^ swA));
            const half8 b1 = *(const half8*)(pB1 + (kb ^ swA));
            const half8 ad = *(const half8*)(pD + (kb ^ swD));
            acc[0][0] = __builtin_amdgcn_mfma_f32_16x16x32_f16(a0, b0, acc[0][0], 0, 0, 0);
            acc[0][1] = __builtin_amdgcn_mfma_f32_16x16x32_f16(a0, b1, acc[0][1], 0, 0, 0);
            acc[1][0] = __builtin_amdgcn_mfma_f32_16x16x32_f16(a1, b0, acc[1][0], 0, 0, 0);
            acc[1][1] = __builtin_amdgcn_mfma_f32_16x16x32_f16(a1, b1, acc[1][1], 0, 0, 0);
            accx = __builtin_amdgcn_mfma_f32_16x16x32_f16(ad, wm ? b1 : b0, accx, 0, 0, 0);
        }

        // ---- cell update: lane holds i,f,g,o in acc[mt2][nt2][0..3]; c in registers ----
        #pragma unroll
        for (int mt2 = 0; mt2 < 2; ++mt2) {
            const int sg = cb * 16 + 8 * wm + 4 * mt2 + lh;
            #pragma unroll
            for (int nt2 = 0; nt2 < 2; ++nt2) {
                const int row = g * 64 + (2 * wn + nt2) * 16 + lr;
                const float iv = sigmoidf_(acc[mt2][nt2][0] + bi[mt2]);
                const float fv = sigmoidf_(acc[mt2][nt2][1] + bf[mt2]);
                const float gv = tanhf_(acc[mt2][nt2][2] + bg[mt2]);
                const float ov = sigmoidf_(acc[mt2][nt2][3] + bo[mt2]);
                const float cnew = fv * creg[mt2][nt2] + iv * gv;
                const float hnew = ov * tanhf_(cnew);
                creg[mt2][nt2] = cnew;
                hout[row * 512 + (sg ^ ((row & 7) << 3))] = (_Float16)hnew;
            }
        }

        // ---- x_{t-1} = dense(h_{t-1}) -> out[:, t-2, :] ----
        if (t >= 2 && lh == 0) {
            const int row = g * 64 + ntx * 16 + lr;
            float* o = &out[((size_t)row * T_STEPS + (t - 2)) * FDIM + cb * 4];
            o[0] = accx[0] + bd[0];
            o[1] = accx[1] + bd[1];
            o[2] = accx[2] + bd[2];
            o[3] = accx[3] + bd[3];
        }

        __syncthreads();   // drains vmcnt: h stores complete before publish
        if (tid == 0)
            __hip_atomic_fetch_add(myctr, 1u, __ATOMIC_RELEASE, __HIP_MEMORY_SCOPE_AGENT);
    }

    // ---- epilogue: x_T = dense(h_T) -> out[:, T-1, :] ----
    {
        if (tid == 0) {
            while (__hip_atomic_load(myctr, __ATOMIC_ACQUIRE, __HIP_MEMORY_SCOPE_AGENT) < 32u * (unsigned)T_STEPS)
                __builtin_amdgcn_s_sleep(1);
        }
        __syncthreads();
        const _Float16* hin = hb0;  // T even -> h_T in buf 0
        const char* gh = (const char*)hin + (size_t)g * 65536;
        #pragma unroll
        for (int i = 0; i < 16; ++i) {
            const int idx = i * 256 + tid;
            gload_lds16(gh + idx * 16, smem + LDS_H + idx * 16);
        }
        __syncthreads();

        f4_t accx = {};
        #pragma unroll
        for (int kt = 0; kt < 16; ++kt) {
            const int kb = kt * 64 + lh * 16;
            const half8 ad = *(const half8*)(pD + (kb ^ swD));
            const half8 b = *(const half8*)(pBx + (kb ^ swA));
            accx = __builtin_amdgcn_mfma_f32_16x16x32_f16(ad, b, accx, 0, 0, 0);
        }
        if (lh == 0) {
            const int row = g * 64 + ntx * 16 + lr;
            float* o = &out[((size_t)row * T_STEPS + (T_STEPS - 1)) * FDIM + cb * 4];
            o[0] = accx[0] + bd[0];
            o[1] = accx[1] + bd[1];
            o[2] = accx[2] + bd[2];
            o[3] = accx[3] + bd[3];
        }
    }
}

extern "C" void kernel_launch(void* const* d_in, const int* in_sizes, int n_in,
                              void* d_out, int out_size, void* d_ws, size_t ws_size,
                              hipStream_t stream)
{
    const float* h0      = (const float*)d_in[0];
    const float* c0      = (const float*)d_in[1];
    const float* W_ih    = (const float*)d_in[2];
    const float* W_hh    = (const float*)d_in[3];
    const float* b_ih    = (const float*)d_in[4];
    const float* b_hh    = (const float*)d_in[5];
    const float* W_dense = (const float*)d_in[6];
    const float* b_dense = (const float*)d_in[7];
    float* out = (float*)d_out;
    char* ws = (char*)d_ws;

    _Float16* Wperm = (_Float16*)(ws + OFF_WPERM);
    _Float16* Wdh   = (_Float16*)(ws + OFF_WDH);
    float*    bcomb = (float*)(ws + OFF_BCOMB);
    _Float16* hb0   = (_Float16*)(ws + OFF_HBUF0);
    _Float16* hb1   = (_Float16*)(ws + OFF_HBUF1);
    unsigned* ctr   = (unsigned*)(ws + OFF_CTR);

    hipMemsetAsync(ctr, 0, 1024, stream);
    k_prep_w<<<2048, 256, 0, stream>>>(W_ih, W_hh, b_ih, b_hh, W_dense, b_dense, Wperm, bcomb);
    k_prep_misc<<<FDIM + BDIM, 256, 0, stream>>>(W_dense, h0, Wdh, hb0);
    k_persist<<<dim3(32, 8), 256, 0, stream>>>(Wperm, Wdh, bcomb, b_dense, c0, hb0, hb1, out, ctr);
}

// Round 4
// 2812.104 us; speedup vs baseline: 3.1015x; 3.1015x over previous
//
#include <hip/hip_runtime.h>
#include <hip/hip_fp16.h>

#define T_STEPS 512
#define BDIM 512
#define LDIM 512
#define FDIM 128

typedef _Float16 half8 __attribute__((ext_vector_type(8)));
typedef float f4_t __attribute__((ext_vector_type(4)));

// workspace offsets (bytes), all 16B-aligned
#define OFF_WPERM   0u          // 2048*512*2   = 2097152
#define OFF_WDH     2097152u    // 128*512*2    = 131072
#define OFF_BCOMB   2228224u    // 2048*4       = 8192
#define OFF_HBUF0   2236416u    // 512*512*2    = 524288
#define OFF_HBUF1   2760704u    // 512*512*2
#define OFF_FLAGS   3284992u    // 8 groups * 32 * 4B = 1024
// total ~3.3 MB

__device__ __forceinline__ float sigmoidf_(float x) { return 1.f / (1.f + __expf(-x)); }
__device__ __forceinline__ float tanhf_(float x) { return 1.f - 2.f / (__expf(2.f * x) + 1.f); }

__device__ __forceinline__ void gload_lds16(const void* g, void* l) {
    __builtin_amdgcn_global_load_lds(
        (const __attribute__((address_space(1))) void*)g,
        (__attribute__((address_space(3))) void*)l, 16, 0, 0);
}

// relaxed agent-scope ops: cache-bypass to the device coherence point (L3) — NO L2 wb/inv fences
// (R1's ACQ/REL agent fences caused buffer_wbl2/buffer_inv storms: 2GB HBM traffic/step)
__device__ __forceinline__ unsigned long long aload64(const void* p) {
    return __hip_atomic_load((unsigned long long*)p, __ATOMIC_RELAXED, __HIP_MEMORY_SCOPE_AGENT);
}
__device__ __forceinline__ unsigned aload32(const void* p) {
    return __hip_atomic_load((unsigned*)p, __ATOMIC_RELAXED, __HIP_MEMORY_SCOPE_AGENT);
}
__device__ __forceinline__ void astore32(void* p, unsigned v) {
    __hip_atomic_store((unsigned*)p, v, __ATOMIC_RELAXED, __HIP_MEMORY_SCOPE_AGENT);
}

// ---------------- precompute: W_perm = permuted+swizzled fp16 of (W_hh + W_ih@W_dense), b_comb ----------------
__global__ __launch_bounds__(256) void k_prep_w(
    const float* __restrict__ W_ih, const float* __restrict__ W_hh,
    const float* __restrict__ b_ih, const float* __restrict__ b_hh,
    const float* __restrict__ W_dense, const float* __restrict__ b_dense,
    _Float16* __restrict__ Wperm, float* __restrict__ bcomb)
{
    __shared__ float ih[FDIM];
    const int pr = blockIdx.x;            // 0..2047
    const int gate = pr & 3, sg = pr >> 2;
    const int j = gate * 512 + sg;        // original gate row
    const int tid = threadIdx.x;
    if (tid < FDIM) ih[tid] = W_ih[j * FDIM + tid];
    __syncthreads();
    const int k0 = tid * 2;
    float a0 = W_hh[(size_t)j * LDIM + k0];
    float a1 = W_hh[(size_t)j * LDIM + k0 + 1];
    for (int f = 0; f < FDIM; ++f) {
        const float w = ih[f];
        a0 += w * W_dense[f * LDIM + k0];
        a1 += w * W_dense[f * LDIM + k0 + 1];
    }
    const int s = (pr & 7) << 3;          // element-level XOR swizzle
    Wperm[(size_t)pr * LDIM + (k0 ^ s)] = (_Float16)a0;
    Wperm[(size_t)pr * LDIM + (k0 ^ s) + 1] = (_Float16)a1;
    if (tid == 0) {
        float acc = b_ih[j] + b_hh[j];
        for (int f = 0; f < FDIM; ++f) acc += ih[f] * b_dense[f];
        bcomb[j] = acc;
    }
}

// ---------------- precompute: fp16 swizzled W_dense copy + fp16 swizzled h0 ----------------
__global__ __launch_bounds__(256) void k_prep_misc(
    const float* __restrict__ W_dense, const float* __restrict__ h0,
    _Float16* __restrict__ Wdh, _Float16* __restrict__ hbuf0)
{
    const int bid = blockIdx.x, tid = threadIdx.x;
    const int k0 = tid * 2;
    if (bid < FDIM) {
        const int f = bid; const int s = (f & 7) << 3;
        Wdh[f * LDIM + (k0 ^ s)] = (_Float16)W_dense[f * LDIM + k0];
        Wdh[f * LDIM + (k0 ^ s) + 1] = (_Float16)W_dense[f * LDIM + k0 + 1];
    } else {
        const int r = bid - FDIM; const int s = (r & 7) << 3;
        hbuf0[r * LDIM + (k0 ^ s)] = (_Float16)h0[r * LDIM + k0];
        hbuf0[r * LDIM + (k0 ^ s) + 1] = (_Float16)h0[r * LDIM + k0 + 1];
    }
}

// ---------------- persistent recurrence kernel ----------------
// grid: (32 col-blocks, 8 row-groups) = 256 blocks = 1/CU (132KB LDS); block: 256 thr = 4 waves 2x2
#define LDS_W   0
#define LDS_WD  65536
#define LDS_H   69632
#define LDS_TOT 135168

// stage 64KB h slice: relaxed agent 8B loads (bypass stale L1/L2) -> LDS, in 4 chunks of 8
__device__ __forceinline__ void stage_h(char* smem, const char* gh, int tid) {
    #pragma unroll
    for (int ch = 0; ch < 4; ++ch) {
        unsigned long long tmp[8];
        #pragma unroll
        for (int r = 0; r < 8; ++r) tmp[r] = aload64(gh + ((ch * 8 + r) * 256 + tid) * 8);
        #pragma unroll
        for (int r = 0; r < 8; ++r)
            *(unsigned long long*)(smem + LDS_H + ((ch * 8 + r) * 256 + tid) * 8) = tmp[r];
    }
}

__global__ __launch_bounds__(256, 1) void k_persist(
    const _Float16* __restrict__ Wperm, const _Float16* __restrict__ Wdh,
    const float* __restrict__ bcomb, const float* __restrict__ bdense,
    const float* __restrict__ c0,
    _Float16* __restrict__ hb0, _Float16* __restrict__ hb1,
    float* __restrict__ out, unsigned* __restrict__ flags)
{
    __shared__ __align__(16) char smem[LDS_TOT];
    const int cb = blockIdx.x;      // 0..31 gate-col block
    const int g = blockIdx.y;       // 0..7 row group
    const int tid = threadIdx.x;
    const int w = tid >> 6, lane = tid & 63;
    const int wm = w >> 1, wn = w & 1;
    const int lr = lane & 15, lh = lane >> 4;

    // ---- one-time: stage W slice (64KB) + Wd slice (4KB) into LDS ----
    {
        const char* gw = (const char*)Wperm + (size_t)cb * 65536;
        #pragma unroll
        for (int i = 0; i < 16; ++i)
            gload_lds16(gw + (i * 256 + tid) * 16, smem + LDS_W + (i * 256 + tid) * 16);
        const char* gd = (const char*)Wdh + (size_t)cb * 4096;
        gload_lds16(gd + tid * 16, smem + LDS_WD + tid * 16);
    }

    // ---- hoist biases + c-state into registers ----
    float bi[2], bf[2], bg[2], bo[2];
    float creg[2][2];
    #pragma unroll
    for (int mt2 = 0; mt2 < 2; ++mt2) {
        const int sg = cb * 16 + 8 * wm + 4 * mt2 + lh;
        bi[mt2] = bcomb[0 * 512 + sg];
        bf[mt2] = bcomb[1 * 512 + sg];
        bg[mt2] = bcomb[2 * 512 + sg];
        bo[mt2] = bcomb[3 * 512 + sg];
        #pragma unroll
        for (int nt2 = 0; nt2 < 2; ++nt2) {
            const int row = g * 64 + (2 * wn + nt2) * 16 + lr;
            creg[mt2][nt2] = c0[(size_t)row * LDIM + sg];
        }
    }
    float bd[4];
    #pragma unroll
    for (int j = 0; j < 4; ++j) bd[j] = bdense[cb * 4 + j];

    const int ntx = 2 * wn + wm;
    const int swA = (lr & 7) << 4;
    const int swD = ((cb * 4 + lr) & 7) << 4;
    const char* pA0 = smem + LDS_W + ((2 * wm + 0) * 16 + lr) * 1024;
    const char* pA1 = smem + LDS_W + ((2 * wm + 1) * 16 + lr) * 1024;
    const char* pB0 = smem + LDS_H + ((2 * wn + 0) * 16 + lr) * 1024;
    const char* pB1 = smem + LDS_H + ((2 * wn + 1) * 16 + lr) * 1024;
    const char* pBx = smem + LDS_H + (ntx * 16 + lr) * 1024;
    const char* pD  = smem + LDS_WD + lr * 1024;

    unsigned* myflags = flags + g * 32;

    // ---- prologue: stage h0 ----
    stage_h(smem, (const char*)hb0 + (size_t)g * 65536, tid);
    __syncthreads();

    for (int t = 1; t <= T_STEPS; ++t) {
        char* hout = (char*)((t & 1) ? hb1 : hb0);

        // ---- gates GEMM ----
        f4_t acc[2][2] = {};
        #pragma unroll
        for (int kt = 0; kt < 16; ++kt) {
            const int kb = kt * 64 + lh * 16;
            const half8 a0 = *(const half8*)(pA0 + (kb ^ swA));
            const half8 a1 = *(const half8*)(pA1 + (kb ^ swA));
            const half8 b0 = *(const half8*)(pB0 + (kb ^ swA));
            const half8 b1 = *(const half8*)(pB1 + (kb ^ swA));
            acc[0][0] = __builtin_amdgcn_mfma_f32_16x16x32_f16(a0, b0, acc[0][0], 0, 0, 0);
            acc[0][1] = __builtin_amdgcn_mfma_f32_16x16x32_f16(a0, b1, acc[0][1], 0, 0, 0);
            acc[1][0] = __builtin_amdgcn_mfma_f32_16x16x32_f16(a1, b0, acc[1][0], 0, 0, 0);
            acc[1][1] = __builtin_amdgcn_mfma_f32_16x16x32_f16(a1, b1, acc[1][1], 0, 0, 0);
        }

        // ---- cell update + packed h publish (relaxed agent 4B stores -> L3) ----
        #pragma unroll
        for (int mt2 = 0; mt2 < 2; ++mt2) {
            const int sg = cb * 16 + 8 * wm + 4 * mt2 + lh;
            #pragma unroll
            for (int nt2 = 0; nt2 < 2; ++nt2) {
                const int row = g * 64 + (2 * wn + nt2) * 16 + lr;
                const float iv = sigmoidf_(acc[mt2][nt2][0] + bi[mt2]);
                const float fv = sigmoidf_(acc[mt2][nt2][1] + bf[mt2]);
                const float gv = tanhf_(acc[mt2][nt2][2] + bg[mt2]);
                const float ov = sigmoidf_(acc[mt2][nt2][3] + bo[mt2]);
                const float cnew = fv * creg[mt2][nt2] + iv * gv;
                const float hnew = ov * tanhf_(cnew);
                creg[mt2][nt2] = cnew;
                const unsigned u = (unsigned)__builtin_bit_cast(unsigned short, (_Float16)hnew);
                const unsigned up = (unsigned)__shfl_xor((int)u, 16);
                if ((lh & 1) == 0) {   // even-lh lanes store (col sg even, pairs with sg+1)
                    const unsigned word = u | (up << 16);
                    astore32(hout + row * 1024 + (sg ^ ((row & 7) << 3)) * 2, word);
                }
            }
        }

        // ---- x_{t-1} = dense(h_{t-1}) MFMA (off critical path; hides store drain) ----
        f4_t accx = {};
        if (t >= 2) {
            #pragma unroll
            for (int kt = 0; kt < 16; ++kt) {
                const int kb = kt * 64 + lh * 16;
                const half8 ad = *(const half8*)(pD + (kb ^ swD));
                const half8 b = *(const half8*)(pBx + (kb ^ swA));
                accx = __builtin_amdgcn_mfma_f32_16x16x32_f16(ad, b, accx, 0, 0, 0);
            }
        }

        __syncthreads();   // drains vmcnt across all waves: h stores are at L3 before flag
        if (tid == 0) astore32(myflags + cb, (unsigned)t);

        if (t >= 2 && lh == 0) {
            const int row = g * 64 + ntx * 16 + lr;
            float* o = &out[((size_t)row * T_STEPS + (t - 2)) * FDIM + cb * 4];
            o[0] = accx[0] + bd[0];
            o[1] = accx[1] + bd[1];
            o[2] = accx[2] + bd[2];
            o[3] = accx[3] + bd[3];
        }

        // ---- wave 0 polls all 32 producer flags of this group (relaxed loads, no fences) ----
        if (w == 0) {
            for (;;) {
                const unsigned v = (lane < 32) ? aload32(myflags + lane) : 0xffffffffu;
                if (__all(v >= (unsigned)t)) break;
                __builtin_amdgcn_s_sleep(1);
            }
        }
        __syncthreads();

        // ---- stage h_t for next iteration (or for epilogue) ----
        stage_h(smem, (const char*)((t & 1) ? hb1 : hb0) + (size_t)g * 65536, tid);
        __syncthreads();
    }

    // ---- epilogue: x_T = dense(h_T) -> out[:, T-1, :] ----
    {
        f4_t accx = {};
        #pragma unroll
        for (int kt = 0; kt < 16; ++kt) {
            const int kb = kt * 64 + lh * 16;
            const half8 ad = *(const half8*)(pD + (kb ^ swD));
            const half8 b = *(const half8*)(pBx + (kb ^ swA));
            accx = __builtin_amdgcn_mfma_f32_16x16x32_f16(ad, b, accx, 0, 0, 0);
        }
        if (lh == 0) {
            const int row = g * 64 + ntx * 16 + lr;
            float* o = &out[((size_t)row * T_STEPS + (T_STEPS - 1)) * FDIM + cb * 4];
            o[0] = accx[0] + bd[0];
            o[1] = accx[1] + bd[1];
            o[2] = accx[2] + bd[2];
            o[3] = accx[3] + bd[3];
        }
    }
}

extern "C" void kernel_launch(void* const* d_in, const int* in_sizes, int n_in,
                              void* d_out, int out_size, void* d_ws, size_t ws_size,
                              hipStream_t stream)
{
    const float* h0      = (const float*)d_in[0];
    const float* c0      = (const float*)d_in[1];
    const float* W_ih    = (const float*)d_in[2];
    const float* W_hh    = (const float*)d_in[3];
    const float* b_ih    = (const float*)d_in[4];
    const float* b_hh    = (const float*)d_in[5];
    const float* W_dense = (const float*)d_in[6];
    const float* b_dense = (const float*)d_in[7];
    float* out = (float*)d_out;
    char* ws = (char*)d_ws;

    _Float16* Wperm = (_Float16*)(ws + OFF_WPERM);
    _Float16* Wdh   = (_Float16*)(ws + OFF_WDH);
    float*    bcomb = (float*)(ws + OFF_BCOMB);
    _Float16* hb0   = (_Float16*)(ws + OFF_HBUF0);
    _Float16* hb1   = (_Float16*)(ws + OFF_HBUF1);
    unsigned* flags = (unsigned*)(ws + OFF_FLAGS);

    hipMemsetAsync(flags, 0, 1024, stream);
    k_prep_w<<<2048, 256, 0, stream>>>(W_ih, W_hh, b_ih, b_hh, W_dense, b_dense, Wperm, bcomb);
    k_prep_misc<<<FDIM + BDIM, 256, 0, stream>>>(W_dense, h0, Wdh, hb0);
    k_persist<<<dim3(32, 8), 256, 0, stream>>>(Wperm, Wdh, bcomb, b_dense, c0, hb0, hb1, out, flags);
}